// Round 6
// baseline (267.009 us; speedup 1.0000x reference)
//
#include <hip/hip_runtime.h>
#include <math.h>

// GATConvQ inference: xw = x@W (bf16 MFMA, bf16 xwb, fused ai/aj epilogue);
// dst-CSR counting sort; one wave per dst node: segment softmax + aggregate.
// v6: gemm stores C via LDS (coalesced uint4) + computes ai/aj in-kernel;
// aggregate drops max-subtraction (softmax shift-invariant, scores bounded)
// and uses uint4/float2 packed inner loop.

#define NEG_SLOPE 0.2f
#define DEG_CAP 96   // fast-path max degree; 1+Poisson(6) tail << 96

typedef short bf8_t __attribute__((ext_vector_type(8)));   // 8 bf16 (4 VGPR)
typedef float f4_t  __attribute__((ext_vector_type(4)));   // MFMA C/D

__device__ __forceinline__ unsigned bf16rne(float f) {
    unsigned u = __float_as_uint(f);
    return (u + 0x7fffu + ((u >> 16) & 1u)) >> 16;
}
__device__ __forceinline__ float bf2f(unsigned short u) {
    return __uint_as_float(((unsigned)u) << 16);
}

// ---- W swizzle: wsw[c][q][n][j] = bf16(W[c*32 + q*8 + j][n]), 16384 elems --
__global__ void wconv_kernel(const float* __restrict__ w, ushort* __restrict__ wsw)
{
    int o = blockIdx.x * 256 + threadIdx.x;     // 64 blocks x 256
    int c = o >> 12, q = (o >> 10) & 3, n = (o >> 3) & 127, j = o & 7;
    float f = w[(c * 32 + q * 8 + j) * 128 + n];
    wsw[o] = (ushort)bf16rne(f);
}

// ------- GEMM: xwb[N,128](bf16) = x @ W, fused ai/aj score halves ----------
__global__ __launch_bounds__(256) void gemm_xw_kernel(
    const float* __restrict__ x, const ushort* __restrict__ wsw,
    const float* __restrict__ att, ushort* __restrict__ xwb,
    float* __restrict__ ai, float* __restrict__ aj, int n)
{
    __shared__ ushort alds[128 * 136];   // 34816 B, row pad 8 bf16
    __shared__ ushort blds[16384];       // 32768 B: B frags, then C tile
    __shared__ float atts[256];
    const int t = threadIdx.x;
    const int row0 = blockIdx.x * 128;

    atts[t] = att[t];   // 256 floats = [h][32]

    // stage B (already bf16 + swizzled)
    const uint4* ws4 = (const uint4*)wsw;
    uint4* bl4 = (uint4*)blds;
#pragma unroll
    for (int j = 0; j < 8; j++) bl4[j * 256 + t] = ws4[j * 256 + t];

    // stage A: coalesced float4 loads, convert to bf16 rne
#pragma unroll
    for (int j = 0; j < 16; j++) {
        int idx = j * 256 + t;
        int row = idx >> 5, kq = idx & 31;
        float4 v = make_float4(0.f, 0.f, 0.f, 0.f);
        if (row0 + row < n)
            v = *(const float4*)(x + (size_t)(row0 + row) * 128 + kq * 4);
        uint2 pk;
        pk.x = bf16rne(v.x) | (bf16rne(v.y) << 16);
        pk.y = bf16rne(v.z) | (bf16rne(v.w) << 16);
        *(uint2*)((char*)alds + row * 272 + kq * 8) = pk;
    }
    __syncthreads();

    const int wave = t >> 6, lane = t & 63;
    const int m = lane & 15, q = lane >> 4;
    const int wrow = wave * 32;

    f4_t acc[2][8];
#pragma unroll
    for (int rt = 0; rt < 2; rt++)
#pragma unroll
        for (int ct = 0; ct < 8; ct++) acc[rt][ct] = (f4_t)0.f;

#pragma unroll
    for (int c = 0; c < 4; c++) {
        bf8_t a0 = *(const bf8_t*)((const char*)alds + (wrow + m) * 272 + c * 64 + q * 16);
        bf8_t a1 = *(const bf8_t*)((const char*)alds + (wrow + 16 + m) * 272 + c * 64 + q * 16);
#pragma unroll
        for (int ct = 0; ct < 8; ct++) {
            bf8_t b = *(const bf8_t*)((const char*)blds + c * 8192 + q * 2048 + (ct * 16 + m) * 16);
            acc[0][ct] = __builtin_amdgcn_mfma_f32_16x16x32_bf16(a0, b, acc[0][ct], 0, 0, 0);
            acc[1][ct] = __builtin_amdgcn_mfma_f32_16x16x32_bf16(a1, b, acc[1][ct], 0, 0, 0);
        }
    }

    __syncthreads();   // all waves done reading blds (B frags)
    // write C tile bf16 into blds[row][col] (C/D layout: col=lane&15,
    // row = quad*4 + reg)
#pragma unroll
    for (int rt = 0; rt < 2; rt++)
#pragma unroll
        for (int r = 0; r < 4; r++) {
            int rl = wrow + rt * 16 + q * 4 + r;
            ushort* cp = blds + rl * 128 + m;
#pragma unroll
            for (int ct = 0; ct < 8; ct++)
                cp[ct * 16] = (ushort)bf16rne(acc[rt][ct][r]);
        }
    __syncthreads();

    // coalesced global store of the C tile: 8 x uint4 per thread
    const uint4* c4 = (const uint4*)blds;
#pragma unroll
    for (int j = 0; j < 8; j++) {
        int cidx = j * 256 + t;
        int row = cidx >> 4;
        if (row0 + row < n)
            *((uint4*)(xwb + (size_t)(row0 + row) * 128) + (cidx & 15)) = c4[cidx];
    }

    // fused ai/aj: thread t handles (row,h) pairs p = t*4 .. t*4+3
    float s0p[4], s1p[4];
#pragma unroll
    for (int i = 0; i < 4; i++) {
        int p = t * 4 + i;
        int row = p >> 3, h = p & 7;
        const ushort* xr = blds + row * 128 + h * 16;
        float a0 = 0.f, a1 = 0.f;
#pragma unroll
        for (int c = 0; c < 16; c++) {
            float f = bf2f(xr[c]);
            a0 += f * atts[h * 32 + c];
            a1 += f * atts[h * 32 + 16 + c];
        }
        s0p[i] = a0; s1p[i] = a1;
    }
    int gp = row0 * 8 + t * 4;
    if (gp + 3 < n * 8) {
        *(float4*)(ai + gp) = make_float4(s0p[0], s0p[1], s0p[2], s0p[3]);
        *(float4*)(aj + gp) = make_float4(s1p[0], s1p[1], s1p[2], s1p[3]);
    } else {
#pragma unroll
        for (int i = 0; i < 4; i++)
            if (gp + i < n * 8) { ai[gp + i] = s0p[i]; aj[gp + i] = s1p[i]; }
    }
}

// ---------------- CSR build: histogram -> scan -> scatter -------------------
__global__ void hist_kernel(const int* __restrict__ dstp,
                            int* __restrict__ counts, int e)
{
    int i = blockIdx.x * 256 + threadIdx.x;
    if (i < e) atomicAdd(&counts[dstp[i]], 1);
}

__global__ __launch_bounds__(256) void scan1_kernel(
    const int* __restrict__ counts, int* __restrict__ rowptr,
    int* __restrict__ blk, int n)
{
    __shared__ int wsum[4];
    const int t = threadIdx.x;
    const int lane = t & 63, w = t >> 6;
    const int base = blockIdx.x * 1024 + t * 4;
    int v[4];
#pragma unroll
    for (int i = 0; i < 4; i++) {
        int idx = base + i;
        v[i] = (idx < n) ? counts[idx] : 0;
    }
    int tsum = v[0] + v[1] + v[2] + v[3];
    int xv = tsum;
#pragma unroll
    for (int off = 1; off < 64; off <<= 1) {
        int y = __shfl_up(xv, off);
        if (lane >= off) xv += y;
    }
    if (lane == 63) wsum[w] = xv;
    __syncthreads();
    int woff = 0;
    for (int i = 0; i < w; i++) woff += wsum[i];
    int run = woff + xv - tsum;
#pragma unroll
    for (int i = 0; i < 4; i++) {
        int idx = base + i;
        if (idx < n) rowptr[idx] = run;
        run += v[i];
    }
    if (t == 255) blk[blockIdx.x] = woff + xv;
}

__global__ __launch_bounds__(128) void scan2_kernel(int* __restrict__ blk, int nb)
{
    __shared__ int w0tot;
    const int t = threadIdx.x;
    const int lane = t & 63, w = t >> 6;
    int v = (t < nb) ? blk[t] : 0;
    int xv = v;
#pragma unroll
    for (int off = 1; off < 64; off <<= 1) {
        int y = __shfl_up(xv, off);
        if (lane >= off) xv += y;
    }
    if (w == 0 && lane == 63) w0tot = xv;
    __syncthreads();
    if (w == 1) xv += w0tot;
    if (t < nb) blk[t] = xv - v;
}

__global__ void scan3_kernel(int* __restrict__ rowptr, const int* __restrict__ blk,
                             int n, int e)
{
    int i = blockIdx.x * 256 + threadIdx.x;
    if (i < n) rowptr[i] += blk[i >> 10];
    if (i == 0) rowptr[n] = e;
}

__global__ void scatter_kernel(const int* __restrict__ srcp, const int* __restrict__ dstp,
                               const int* __restrict__ rowptr, int* __restrict__ cursor,
                               int* __restrict__ ssrc, int e)
{
    int i = blockIdx.x * 256 + threadIdx.x;
    if (i >= e) return;
    int d = dstp[i];
    int pos = rowptr[d] + atomicAdd(&cursor[d], 1);
    ssrc[pos] = srcp[i];
}

// ---------------- one wave per dst node: softmax + aggregate ----------------
// Softmax computed WITHOUT max subtraction: scores are small (|alpha| < ~10,
// exp safe in fp32) and softmax is shift-invariant.
__global__ __launch_bounds__(256) void aggregate_kernel(
    const ushort* __restrict__ xwb, const float* __restrict__ ai,
    const float* __restrict__ aj, const int* __restrict__ rowptr,
    const int* __restrict__ ssrc, const float* __restrict__ bias,
    float* __restrict__ out, int n)
{
    __shared__ float salpha[4][DEG_CAP * 8];
    const int wv = threadIdx.x >> 6;
    const int lane = threadIdx.x & 63;
    const int wid = (blockIdx.x * blockDim.x + threadIdx.x) >> 6;  // node id
    if (wid >= n) return;
    const int start = rowptr[wid];
    const int end = rowptr[wid + 1];
    const int deg = end - start;

    if (deg <= DEG_CAP) {
        float* As = salpha[wv];
        int sv0 = (start + lane < end) ? ssrc[start + lane] : 0;
        int sv1 = (start + 64 + lane < end) ? ssrc[start + 64 + lane] : 0;

        const int h = lane & 7;
        const int g = lane >> 3;
        const float a_i = ai[wid * 8 + h];

        // pass A: exp(alpha) into LDS stash + per-head sum.
        // Wave-uniform trip count: every __shfl fully active.
        const int kmax = (deg + 7) >> 3;
        float ssum = 0.f;
        for (int k = 0; k < kmax; k++) {
            int eo = g + 8 * k;
            int s = (eo < 64) ? __shfl(sv0, eo & 63) : __shfl(sv1, eo & 63);
            if (eo < deg) {
                float a = a_i + aj[s * 8 + h];
                a = (a >= 0.f) ? a : NEG_SLOPE * a;
                float wgt = __expf(a);
                As[eo * 8 + h] = wgt;
                ssum += wgt;
            }
        }
        ssum += __shfl_xor(ssum, 8);
        ssum += __shfl_xor(ssum, 16);
        ssum += __shfl_xor(ssum, 32);

        // pass B: 4 edges/iter, 16 lanes/edge; lane handles 8 channels
        // (head hch) of edge (k*4 + eg)
        const int eg = lane >> 4;
        const int c16 = lane & 15;
        const int hch = c16 >> 1;
        const float inv = 1.f / __shfl(ssum, hch);
        float2 acc2[4];
#pragma unroll
        for (int j = 0; j < 4; j++) acc2[j] = make_float2(0.f, 0.f);

        const int kmax3 = (deg + 3) >> 2;
#pragma unroll 2
        for (int k = 0; k < kmax3; k++) {
            int e = k * 4 + eg;
            int s = (e < 64) ? __shfl(sv0, e & 63) : __shfl(sv1, e & 63);
            float wgt = (e < deg) ? As[e * 8 + hch] : 0.f;
            uint4 xv = *(const uint4*)(xwb + (size_t)s * 128 + c16 * 8);
            acc2[0].x += wgt * __uint_as_float(xv.x << 16);
            acc2[0].y += wgt * __uint_as_float(xv.x & 0xffff0000u);
            acc2[1].x += wgt * __uint_as_float(xv.y << 16);
            acc2[1].y += wgt * __uint_as_float(xv.y & 0xffff0000u);
            acc2[2].x += wgt * __uint_as_float(xv.z << 16);
            acc2[2].y += wgt * __uint_as_float(xv.z & 0xffff0000u);
            acc2[3].x += wgt * __uint_as_float(xv.w << 16);
            acc2[3].y += wgt * __uint_as_float(xv.w & 0xffff0000u);
        }
#pragma unroll
        for (int j = 0; j < 4; j++) {
            acc2[j].x += __shfl_xor(acc2[j].x, 16);
            acc2[j].x += __shfl_xor(acc2[j].x, 32);
            acc2[j].y += __shfl_xor(acc2[j].y, 16);
            acc2[j].y += __shfl_xor(acc2[j].y, 32);
        }
        const int cs = c16 * 8 + eg * 2;
        float2 o;
        o.x = acc2[eg].x * inv + bias[cs];
        o.y = acc2[eg].y * inv + bias[cs + 1];
        *(float2*)(out + (size_t)wid * 128 + cs) = o;
    } else {
        // slow path (deg > DEG_CAP): 2-pass re-gather, no max
        const int h = lane & 7;
        const float a_i = ai[wid * 8 + h];
        float ssum = 0.f;
        for (int eo = lane >> 3; eo < deg; eo += 8) {
            int s = ssrc[start + eo];
            float a = a_i + aj[s * 8 + h];
            a = (a >= 0.f) ? a : NEG_SLOPE * a;
            ssum += __expf(a);
        }
        ssum += __shfl_xor(ssum, 8);
        ssum += __shfl_xor(ssum, 16);
        ssum += __shfl_xor(ssum, 32);
        const float inv = 1.f / ssum;
        const int h0 = lane >> 4;
        const int h1 = 4 + (lane >> 4);
        float acc0 = 0.f, acc1 = 0.f;
        for (int e = start; e < end; e++) {
            int s = ssrc[e];
            float a = a_i + aj[s * 8 + h];
            a = (a >= 0.f) ? a : NEG_SLOPE * a;
            float wv2 = __expf(a) * inv;
            float w0 = __shfl(wv2, h0);
            float w1 = __shfl(wv2, h1);
            const ushort* xr = xwb + (size_t)s * 128;
            acc0 += w0 * bf2f(xr[lane]);
            acc1 += w1 * bf2f(xr[64 + lane]);
        }
        out[(size_t)wid * 128 + lane] = acc0 + bias[lane];
        out[(size_t)wid * 128 + 64 + lane] = acc1 + bias[64 + lane];
    }
}

extern "C" void kernel_launch(void* const* d_in, const int* in_sizes, int n_in,
                              void* d_out, int out_size, void* d_ws, size_t ws_size,
                              hipStream_t stream)
{
    const float* x    = (const float*)d_in[0];
    const int*   ei   = (const int*)d_in[1];   // [2, E] int32
    const float* w    = (const float*)d_in[3];
    const float* att  = (const float*)d_in[4];
    const float* bias = (const float*)d_in[5];
    const int N = in_sizes[0] / 128;
    const int E = in_sizes[1] / 2;
    const int* srcp = ei;
    const int* dstp = ei + E;

    // workspace layout (xwb first: 16B-aligned for uint4 loads)
    ushort* xwb    = (ushort*)d_ws;                   // N*128 bf16
    ushort* wsw    = xwb + (size_t)N * 128;           // 16384 bf16
    float*  ai     = (float*)(wsw + 16384);           // N*8
    float*  aj     = ai + (size_t)N * 8;              // N*8
    int*    counts = (int*)(aj + (size_t)N * 8);      // N
    int*    cursor = counts + N;                      // N
    int*    rowptr = cursor + N;                      // N+1 (reserve N+4)
    int*    blk    = rowptr + (N + 4);                // <=128 (+pad to 256)
    int*    ssrc   = blk + 256;                       // E

    hipMemsetAsync(counts, 0, (size_t)2 * N * sizeof(int), stream);

    wconv_kernel<<<64, 256, 0, stream>>>(w, wsw);
    gemm_xw_kernel<<<(N + 127) / 128, 256, 0, stream>>>(x, wsw, att, xwb, ai, aj, N);
    hist_kernel<<<(E + 255) / 256, 256, 0, stream>>>(dstp, counts, E);
    int nb = (N + 1023) / 1024;
    scan1_kernel<<<nb, 256, 0, stream>>>(counts, rowptr, blk, N);
    scan2_kernel<<<1, 128, 0, stream>>>(blk, nb);
    scan3_kernel<<<(N + 255) / 256, 256, 0, stream>>>(rowptr, blk, N, E);
    scatter_kernel<<<(E + 255) / 256, 256, 0, stream>>>(srcp, dstp, rowptr, cursor, ssrc, E);
    aggregate_kernel<<<(N * 64 + 255) / 256, 256, 0, stream>>>(
        xwb, ai, aj, rowptr, ssrc, bias, (float*)d_out, N);
}

// Round 8
// 246.976 us; speedup vs baseline: 1.0811x; 1.0811x over previous
//
#include <hip/hip_runtime.h>
#include <math.h>

// GATConvQ inference: xw = x@W (bf16 MFMA, bf16 xwb, fused ai/aj epilogue);
// dst-CSR counting sort; one wave per dst node: segment softmax + aggregate.
// v7b: same as v7 but nontemporal store uses a clang ext_vector float2
// (builtin rejects HIP_vector_type float2).

#define NEG_SLOPE 0.2f
#define DEG_CAP 96   // fast-path max degree; 1+Poisson(6) tail << 96

typedef short bf8_t __attribute__((ext_vector_type(8)));   // 8 bf16 (4 VGPR)
typedef float f4_t  __attribute__((ext_vector_type(4)));   // MFMA C/D
typedef float f2_t  __attribute__((ext_vector_type(2)));   // native float2
typedef unsigned short us8_t __attribute__((ext_vector_type(8)));

__device__ __forceinline__ unsigned bf16rne(float f) {
    unsigned u = __float_as_uint(f);
    return (u + 0x7fffu + ((u >> 16) & 1u)) >> 16;
}
__device__ __forceinline__ float bf2f(unsigned short u) {
    return __uint_as_float(((unsigned)u) << 16);
}

// ---- W swizzle: wsw[c][q][n][j] = bf16(W[c*32 + q*8 + j][n]), 16384 elems --
__global__ void wconv_kernel(const float* __restrict__ w, ushort* __restrict__ wsw)
{
    int o = blockIdx.x * 256 + threadIdx.x;     // 64 blocks x 256
    int c = o >> 12, q = (o >> 10) & 3, n = (o >> 3) & 127, j = o & 7;
    float f = w[(c * 32 + q * 8 + j) * 128 + n];
    wsw[o] = (ushort)bf16rne(f);
}

// ------- GEMM: xwb[N,128](bf16) = x @ W, fused ai/aj score halves ----------
__global__ __launch_bounds__(256) void gemm_xw_kernel(
    const float* __restrict__ x, const ushort* __restrict__ wsw,
    const float* __restrict__ att, ushort* __restrict__ xwb,
    float* __restrict__ ai, float* __restrict__ aj, int n)
{
    __shared__ ushort alds[128 * 136];   // 34816 B, row pad 8 bf16
    __shared__ ushort blds[16384];       // 32768 B: B frags, then C tile
    __shared__ float atts[256];
    const int t = threadIdx.x;
    const int row0 = blockIdx.x * 128;

    atts[t] = att[t];   // 256 floats = [h][32]

    // stage B (already bf16 + swizzled)
    const uint4* ws4 = (const uint4*)wsw;
    uint4* bl4 = (uint4*)blds;
#pragma unroll
    for (int j = 0; j < 8; j++) bl4[j * 256 + t] = ws4[j * 256 + t];

    // stage A: coalesced float4 loads, convert to bf16 rne
#pragma unroll
    for (int j = 0; j < 16; j++) {
        int idx = j * 256 + t;
        int row = idx >> 5, kq = idx & 31;
        float4 v = make_float4(0.f, 0.f, 0.f, 0.f);
        if (row0 + row < n)
            v = *(const float4*)(x + (size_t)(row0 + row) * 128 + kq * 4);
        uint2 pk;
        pk.x = bf16rne(v.x) | (bf16rne(v.y) << 16);
        pk.y = bf16rne(v.z) | (bf16rne(v.w) << 16);
        *(uint2*)((char*)alds + row * 272 + kq * 8) = pk;
    }
    __syncthreads();

    const int wave = t >> 6, lane = t & 63;
    const int m = lane & 15, q = lane >> 4;
    const int wrow = wave * 32;

    f4_t acc[2][8];
#pragma unroll
    for (int rt = 0; rt < 2; rt++)
#pragma unroll
        for (int ct = 0; ct < 8; ct++) acc[rt][ct] = (f4_t)0.f;

#pragma unroll
    for (int c = 0; c < 4; c++) {
        bf8_t a0 = *(const bf8_t*)((const char*)alds + (wrow + m) * 272 + c * 64 + q * 16);
        bf8_t a1 = *(const bf8_t*)((const char*)alds + (wrow + 16 + m) * 272 + c * 64 + q * 16);
#pragma unroll
        for (int ct = 0; ct < 8; ct++) {
            bf8_t b = *(const bf8_t*)((const char*)blds + c * 8192 + q * 2048 + (ct * 16 + m) * 16);
            acc[0][ct] = __builtin_amdgcn_mfma_f32_16x16x32_bf16(a0, b, acc[0][ct], 0, 0, 0);
            acc[1][ct] = __builtin_amdgcn_mfma_f32_16x16x32_bf16(a1, b, acc[1][ct], 0, 0, 0);
        }
    }

    __syncthreads();   // all waves done reading blds (B frags)
    // write C tile bf16 into blds[row][col] (C/D layout: col=lane&15,
    // row = quad*4 + reg)
#pragma unroll
    for (int rt = 0; rt < 2; rt++)
#pragma unroll
        for (int r = 0; r < 4; r++) {
            int rl = wrow + rt * 16 + q * 4 + r;
            ushort* cp = blds + rl * 128 + m;
#pragma unroll
            for (int ct = 0; ct < 8; ct++)
                cp[ct * 16] = (ushort)bf16rne(acc[rt][ct][r]);
        }
    __syncthreads();

    // coalesced global store of the C tile: 8 x uint4 per thread
    const uint4* c4 = (const uint4*)blds;
#pragma unroll
    for (int j = 0; j < 8; j++) {
        int cidx = j * 256 + t;
        int row = cidx >> 4;
        if (row0 + row < n)
            *((uint4*)(xwb + (size_t)(row0 + row) * 128) + (cidx & 15)) = c4[cidx];
    }

    // fused ai/aj: thread t handles (row,h) pairs p = t*4 .. t*4+3
    float s0p[4], s1p[4];
#pragma unroll
    for (int i = 0; i < 4; i++) {
        int p = t * 4 + i;
        int row = p >> 3, h = p & 7;
        const ushort* xr = blds + row * 128 + h * 16;
        float a0 = 0.f, a1 = 0.f;
#pragma unroll
        for (int c = 0; c < 16; c++) {
            float f = bf2f(xr[c]);
            a0 += f * atts[h * 32 + c];
            a1 += f * atts[h * 32 + 16 + c];
        }
        s0p[i] = a0; s1p[i] = a1;
    }
    int gp = row0 * 8 + t * 4;
    if (gp + 3 < n * 8) {
        *(float4*)(ai + gp) = make_float4(s0p[0], s0p[1], s0p[2], s0p[3]);
        *(float4*)(aj + gp) = make_float4(s1p[0], s1p[1], s1p[2], s1p[3]);
    } else {
#pragma unroll
        for (int i = 0; i < 4; i++)
            if (gp + i < n * 8) { ai[gp + i] = s0p[i]; aj[gp + i] = s1p[i]; }
    }
}

// ---------------- CSR build: histogram -> scan -> scatter -------------------
__global__ void hist_kernel(const int* __restrict__ dstp,
                            int* __restrict__ counts, int e)
{
    int i = blockIdx.x * 256 + threadIdx.x;
    if (i < e) atomicAdd(&counts[dstp[i]], 1);
}

__global__ __launch_bounds__(256) void scan1_kernel(
    const int* __restrict__ counts, int* __restrict__ rowptr,
    int* __restrict__ blk, int n)
{
    __shared__ int wsum[4];
    const int t = threadIdx.x;
    const int lane = t & 63, w = t >> 6;
    const int base = blockIdx.x * 1024 + t * 4;
    int v[4];
#pragma unroll
    for (int i = 0; i < 4; i++) {
        int idx = base + i;
        v[i] = (idx < n) ? counts[idx] : 0;
    }
    int tsum = v[0] + v[1] + v[2] + v[3];
    int xv = tsum;
#pragma unroll
    for (int off = 1; off < 64; off <<= 1) {
        int y = __shfl_up(xv, off);
        if (lane >= off) xv += y;
    }
    if (lane == 63) wsum[w] = xv;
    __syncthreads();
    int woff = 0;
    for (int i = 0; i < w; i++) woff += wsum[i];
    int run = woff + xv - tsum;
#pragma unroll
    for (int i = 0; i < 4; i++) {
        int idx = base + i;
        if (idx < n) rowptr[idx] = run;
        run += v[i];
    }
    if (t == 255) blk[blockIdx.x] = woff + xv;
}

__global__ __launch_bounds__(128) void scan2_kernel(int* __restrict__ blk, int nb)
{
    __shared__ int w0tot;
    const int t = threadIdx.x;
    const int lane = t & 63, w = t >> 6;
    int v = (t < nb) ? blk[t] : 0;
    int xv = v;
#pragma unroll
    for (int off = 1; off < 64; off <<= 1) {
        int y = __shfl_up(xv, off);
        if (lane >= off) xv += y;
    }
    if (w == 0 && lane == 63) w0tot = xv;
    __syncthreads();
    if (w == 1) xv += w0tot;
    if (t < nb) blk[t] = xv - v;
}

__global__ void scan3_kernel(int* __restrict__ rowptr, const int* __restrict__ blk,
                             int n, int e)
{
    int i = blockIdx.x * 256 + threadIdx.x;
    if (i < n) rowptr[i] += blk[i >> 10];
    if (i == 0) rowptr[n] = e;
}

__global__ void scatter_kernel(const int* __restrict__ srcp, const int* __restrict__ dstp,
                               const int* __restrict__ rowptr, int* __restrict__ cursor,
                               int* __restrict__ ssrc, int e)
{
    int i = blockIdx.x * 256 + threadIdx.x;
    if (i >= e) return;
    int d = dstp[i];
    int pos = rowptr[d] + atomicAdd(&cursor[d], 1);
    ssrc[pos] = srcp[i];
}

// ---------------- one wave per dst node: softmax + aggregate ----------------
// (verbatim v5 structure — measured 56.4us, 0 LDS conflicts, VGPR=20)
__global__ __launch_bounds__(256) void aggregate_kernel(
    const ushort* __restrict__ xwb, const float* __restrict__ ai,
    const float* __restrict__ aj, const int* __restrict__ rowptr,
    const int* __restrict__ ssrc, const float* __restrict__ bias,
    float* __restrict__ out, int n)
{
    __shared__ float salpha[4][DEG_CAP * 8];
    const int wv = threadIdx.x >> 6;
    const int lane = threadIdx.x & 63;
    const int wid = (blockIdx.x * blockDim.x + threadIdx.x) >> 6;  // node id
    if (wid >= n) return;
    const int start = rowptr[wid];
    const int end = rowptr[wid + 1];
    const int deg = end - start;

    if (deg <= DEG_CAP) {
        float* As = salpha[wv];
        int sv0 = (start + lane < end) ? ssrc[start + lane] : 0;
        int sv1 = (start + 64 + lane < end) ? ssrc[start + 64 + lane] : 0;

        const int h = lane & 7;
        const int g = lane >> 3;
        const float a_i = ai[wid * 8 + h];

        // pass 1: wave-uniform trip count; every __shfl fully active
        const int kmax = (deg + 7) >> 3;
        float m = -1e30f;
        for (int k = 0; k < kmax; k++) {
            int eo = g + 8 * k;
            int s = (eo < 64) ? __shfl(sv0, eo & 63) : __shfl(sv1, eo & 63);
            if (eo < deg) {
                float a = a_i + aj[s * 8 + h];
                a = (a >= 0.f) ? a : NEG_SLOPE * a;
                As[eo * 8 + h] = a;
                m = fmaxf(m, a);
            }
        }
        m = fmaxf(m, __shfl_xor(m, 8));
        m = fmaxf(m, __shfl_xor(m, 16));
        m = fmaxf(m, __shfl_xor(m, 32));

        // pass 2: exponentiate in place, per-head sum
        float ssum = 0.f;
        for (int eo = g; eo < deg; eo += 8) {
            float wgt = __expf(As[eo * 8 + h] - m);
            As[eo * 8 + h] = wgt;
            ssum += wgt;
        }
        ssum += __shfl_xor(ssum, 8);
        ssum += __shfl_xor(ssum, 16);
        ssum += __shfl_xor(ssum, 32);

        // pass 3: 4 edges/iter, 16 lanes/edge; lane handles 8 channels
        // (one head) of edge (it*4 + lane>>4)
        const int eg = lane >> 4;          // edge group 0..3
        const int c16 = lane & 15;         // channel chunk: ch 8*c16..+7
        const int hch = c16 >> 1;          // head of this chunk
        float acc[8];
#pragma unroll
        for (int j = 0; j < 8; j++) acc[j] = 0.f;

        const int kmax3 = (deg + 3) >> 2;
        for (int k = 0; k < kmax3; k++) {
            int e = k * 4 + eg;
            int s = (e < 64) ? __shfl(sv0, e & 63) : __shfl(sv1, e & 63);
            float wgt = (e < deg) ? As[e * 8 + hch] : 0.f;
            us8_t xv = *(const us8_t*)(xwb + (size_t)s * 128 + c16 * 8);
#pragma unroll
            for (int j = 0; j < 8; j++)
                acc[j] += wgt * bf2f(xv[j]);
        }
        // reduce the 4 edge groups
#pragma unroll
        for (int j = 0; j < 8; j++) {
            acc[j] += __shfl_xor(acc[j], 16);
            acc[j] += __shfl_xor(acc[j], 32);
        }
        const float inv = 1.f / __shfl(ssum, hch);
        // lane stores channels 8*c16 + 2*eg, +1 (coalesced 512B per node)
        const int cs = c16 * 8 + eg * 2;
        f2_t o;
        o.x = acc[eg * 2] * inv + bias[cs];
        o.y = acc[eg * 2 + 1] * inv + bias[cs + 1];
        __builtin_nontemporal_store(o, (f2_t*)(out + (size_t)wid * 128 + cs));
    } else {
        // slow path (deg > DEG_CAP): 3-pass re-gather
        const int h = lane & 7;
        const float a_i = ai[wid * 8 + h];
        float m = -1e30f;
        for (int eo = lane >> 3; eo < deg; eo += 8) {
            int s = ssrc[start + eo];
            float a = a_i + aj[s * 8 + h];
            a = (a >= 0.f) ? a : NEG_SLOPE * a;
            m = fmaxf(m, a);
        }
        m = fmaxf(m, __shfl_xor(m, 8));
        m = fmaxf(m, __shfl_xor(m, 16));
        m = fmaxf(m, __shfl_xor(m, 32));
        float ssum = 0.f;
        for (int eo = lane >> 3; eo < deg; eo += 8) {
            int s = ssrc[start + eo];
            float a = a_i + aj[s * 8 + h];
            a = (a >= 0.f) ? a : NEG_SLOPE * a;
            ssum += __expf(a - m);
        }
        ssum += __shfl_xor(ssum, 8);
        ssum += __shfl_xor(ssum, 16);
        ssum += __shfl_xor(ssum, 32);
        const float inv = 1.f / ssum;
        const int h0 = lane >> 4;
        const int h1 = 4 + (lane >> 4);
        float acc0 = 0.f, acc1 = 0.f;
        for (int e = start; e < end; e++) {
            int s = ssrc[e];
            float a = a_i + aj[s * 8 + h];
            a = (a >= 0.f) ? a : NEG_SLOPE * a;
            float wv2 = __expf(a - m) * inv;
            float w0 = __shfl(wv2, h0);
            float w1 = __shfl(wv2, h1);
            const ushort* xr = xwb + (size_t)s * 128;
            acc0 += w0 * bf2f(xr[lane]);
            acc1 += w1 * bf2f(xr[64 + lane]);
        }
        out[(size_t)wid * 128 + lane] = acc0 + bias[lane];
        out[(size_t)wid * 128 + 64 + lane] = acc1 + bias[64 + lane];
    }
}

extern "C" void kernel_launch(void* const* d_in, const int* in_sizes, int n_in,
                              void* d_out, int out_size, void* d_ws, size_t ws_size,
                              hipStream_t stream)
{
    const float* x    = (const float*)d_in[0];
    const int*   ei   = (const int*)d_in[1];   // [2, E] int32
    const float* w    = (const float*)d_in[3];
    const float* att  = (const float*)d_in[4];
    const float* bias = (const float*)d_in[5];
    const int N = in_sizes[0] / 128;
    const int E = in_sizes[1] / 2;
    const int* srcp = ei;
    const int* dstp = ei + E;

    // workspace layout (xwb first: 16B-aligned for ushort8 loads)
    ushort* xwb    = (ushort*)d_ws;                   // N*128 bf16
    ushort* wsw    = xwb + (size_t)N * 128;           // 16384 bf16
    float*  ai     = (float*)(wsw + 16384);           // N*8
    float*  aj     = ai + (size_t)N * 8;              // N*8
    int*    counts = (int*)(aj + (size_t)N * 8);      // N
    int*    cursor = counts + N;                      // N
    int*    rowptr = cursor + N;                      // N+1 (reserve N+4)
    int*    blk    = rowptr + (N + 4);                // <=128 (+pad to 256)
    int*    ssrc   = blk + 256;                       // E

    (void)hipMemsetAsync(counts, 0, (size_t)2 * N * sizeof(int), stream);

    wconv_kernel<<<64, 256, 0, stream>>>(w, wsw);
    gemm_xw_kernel<<<(N + 127) / 128, 256, 0, stream>>>(x, wsw, att, xwb, ai, aj, N);
    hist_kernel<<<(E + 255) / 256, 256, 0, stream>>>(dstp, counts, E);
    int nb = (N + 1023) / 1024;
    scan1_kernel<<<nb, 256, 0, stream>>>(counts, rowptr, blk, N);
    scan2_kernel<<<1, 128, 0, stream>>>(blk, nb);
    scan3_kernel<<<(N + 255) / 256, 256, 0, stream>>>(rowptr, blk, N, E);
    scatter_kernel<<<(E + 255) / 256, 256, 0, stream>>>(srcp, dstp, rowptr, cursor, ssrc, E);
    aggregate_kernel<<<(N * 64 + 255) / 256, 256, 0, stream>>>(
        xwb, ai, aj, rowptr, ssrc, bias, (float*)d_out, N);
}